// Round 1
// baseline (568.379 us; speedup 1.0000x reference)
//
#include <hip/hip_runtime.h>
#include <math.h>

// ---------------------------------------------------------------------------
// GCN 3-layer forward for MI355X.
// Strategy: build CSR (dst-grouped) + per-edge norm ONCE per launch, reuse for
// all 3 layers. Dense transform = fp32 tiled GEMM (no fp32 MFMA on CDNA4).
// Aggregation = CSR gather SpMM, one wave per node (no float atomics).
// Layer 3 fuses bias+relu+log_softmax (64 cols == 64 lanes).
// ---------------------------------------------------------------------------

__global__ void hist_kernel(const int* __restrict__ dst, int* __restrict__ counts, int E) {
    int e = blockIdx.x * blockDim.x + threadIdx.x;
    if (e < E) atomicAdd(&counts[dst[e]], 1);
}

__global__ void dinv_kernel(const int* __restrict__ counts, float* __restrict__ dinv, int N) {
    int v = blockIdx.x * blockDim.x + threadIdx.x;
    if (v < N) dinv[v] = rsqrtf((float)counts[v] + 1.0f);  // +1 self loop
}

// Single-block in-place exclusive scan over data[0..n-1]; data[n] = total.
__global__ __launch_bounds__(1024) void scan_kernel(int* data, int n) {
    __shared__ int buf[1024];
    int tid = threadIdx.x;
    int carry = 0;
    for (int base = 0; base < n; base += 1024) {
        int i = base + tid;
        int v = (i < n) ? data[i] : 0;
        buf[tid] = v;
        __syncthreads();
        #pragma unroll
        for (int off = 1; off < 1024; off <<= 1) {
            int t = (tid >= off) ? buf[tid - off] : 0;
            __syncthreads();
            buf[tid] += t;
            __syncthreads();
        }
        int incl = buf[tid];
        int total = buf[1023];
        if (i < n) data[i] = carry + incl - v;   // exclusive
        carry += total;
        __syncthreads();
    }
    if (tid == 0) data[n] = carry;
}

__global__ void initpos_kernel(const int* __restrict__ rowptr, int* __restrict__ pos, int N) {
    int v = blockIdx.x * blockDim.x + threadIdx.x;
    if (v < N) pos[v] = rowptr[v];
}

__global__ void scatter_kernel(const int* __restrict__ src, const int* __restrict__ dst,
                               const float* __restrict__ dinv, int* __restrict__ pos,
                               int* __restrict__ col, float* __restrict__ normv, int E) {
    int e = blockIdx.x * blockDim.x + threadIdx.x;
    if (e >= E) return;
    int s = src[e], d = dst[e];
    int idx = atomicAdd(&pos[d], 1);
    col[idx]   = s;
    normv[idx] = dinv[s] * dinv[d];
}

// C[N][H] = A[N][K] @ B[K][H]; 64x64 tile, K-step 32, 256 threads, 4x4 micro.
__global__ __launch_bounds__(256) void gemm_kernel(const float* __restrict__ A,
                                                   const float* __restrict__ B,
                                                   float* __restrict__ C,
                                                   int N, int K, int H) {
    __shared__ float As[64][33];
    __shared__ float Bs[32][65];
    int row0 = blockIdx.x * 64, col0 = blockIdx.y * 64;
    int tid = threadIdx.x;
    int tx = tid & 15, ty = tid >> 4;
    float acc[4][4] = {};
    for (int k0 = 0; k0 < K; k0 += 32) {
        for (int i = tid; i < 64 * 32; i += 256) {
            int r = i >> 5, c = i & 31;
            int gr = row0 + r;
            As[r][c] = (gr < N) ? A[(size_t)gr * K + k0 + c] : 0.0f;
        }
        for (int i = tid; i < 32 * 64; i += 256) {
            int r = i >> 6, c = i & 63;
            Bs[r][c] = B[(size_t)(k0 + r) * H + col0 + c];
        }
        __syncthreads();
        #pragma unroll
        for (int kk = 0; kk < 32; ++kk) {
            float a[4], b[4];
            #pragma unroll
            for (int i = 0; i < 4; ++i) a[i] = As[ty * 4 + i][kk];
            #pragma unroll
            for (int j = 0; j < 4; ++j) b[j] = Bs[kk][tx * 4 + j];
            #pragma unroll
            for (int i = 0; i < 4; ++i)
                #pragma unroll
                for (int j = 0; j < 4; ++j) acc[i][j] += a[i] * b[j];
        }
        __syncthreads();
    }
    #pragma unroll
    for (int i = 0; i < 4; ++i) {
        int gr = row0 + ty * 4 + i;
        if (gr < N) {
            #pragma unroll
            for (int j = 0; j < 4; ++j)
                C[(size_t)gr * H + col0 + tx * 4 + j] = acc[i][j];
        }
    }
}

// One wave per node, 128 channels via float2. bias+relu fused.
__global__ __launch_bounds__(256) void spmm128_kernel(const float* __restrict__ h,
                                                      const int* __restrict__ rowptr,
                                                      const int* __restrict__ col,
                                                      const float* __restrict__ normv,
                                                      const float* __restrict__ dinv,
                                                      const float* __restrict__ bias,
                                                      float* __restrict__ out, int N) {
    int wid = blockIdx.x * 4 + (threadIdx.x >> 6);
    int lane = threadIdx.x & 63;
    if (wid >= N) return;
    const float2* h2 = (const float2*)h;
    float dv = dinv[wid];
    float w = dv * dv;
    float2 hv = h2[(size_t)wid * 64 + lane];
    float ax = hv.x * w, ay = hv.y * w;
    int beg = rowptr[wid], end = rowptr[wid + 1];
    for (int e = beg; e < end; ++e) {
        int s = col[e];
        float nm = normv[e];
        float2 hs = h2[(size_t)s * 64 + lane];
        ax += hs.x * nm;
        ay += hs.y * nm;
    }
    ax += bias[lane * 2];
    ay += bias[lane * 2 + 1];
    ax = fmaxf(ax, 0.0f);
    ay = fmaxf(ay, 0.0f);
    float2 o;
    o.x = ax; o.y = ay;
    ((float2*)out)[(size_t)wid * 64 + lane] = o;
}

// Layer 3: 64 channels (one per lane) + bias + relu + log_softmax across lanes.
__global__ __launch_bounds__(256) void spmm64_lsm_kernel(const float* __restrict__ h,
                                                         const int* __restrict__ rowptr,
                                                         const int* __restrict__ col,
                                                         const float* __restrict__ normv,
                                                         const float* __restrict__ dinv,
                                                         const float* __restrict__ bias,
                                                         float* __restrict__ out, int N) {
    int wid = blockIdx.x * 4 + (threadIdx.x >> 6);
    int lane = threadIdx.x & 63;
    if (wid >= N) return;
    float dv = dinv[wid];
    float acc = h[(size_t)wid * 64 + lane] * dv * dv;
    int beg = rowptr[wid], end = rowptr[wid + 1];
    for (int e = beg; e < end; ++e) {
        int s = col[e];
        float nm = normv[e];
        acc += h[(size_t)s * 64 + lane] * nm;
    }
    acc += bias[lane];
    acc = fmaxf(acc, 0.0f);
    // log_softmax across the 64 lanes
    float m = acc;
    #pragma unroll
    for (int off = 32; off; off >>= 1) m = fmaxf(m, __shfl_xor(m, off));
    float ex = expf(acc - m);
    float ssum = ex;
    #pragma unroll
    for (int off = 32; off; off >>= 1) ssum += __shfl_xor(ssum, off);
    out[(size_t)wid * 64 + lane] = acc - m - logf(ssum);
}

extern "C" void kernel_launch(void* const* d_in, const int* in_sizes, int n_in,
                              void* d_out, int out_size, void* d_ws, size_t ws_size,
                              hipStream_t stream) {
    const float* x  = (const float*)d_in[0];
    const int*   ei = (const int*)d_in[1];
    const float* W1 = (const float*)d_in[2];
    const float* b1 = (const float*)d_in[3];
    const float* W2 = (const float*)d_in[4];
    const float* b2 = (const float*)d_in[5];
    const float* W3 = (const float*)d_in[6];
    const float* b3 = (const float*)d_in[7];
    float* out = (float*)d_out;

    const int IN = 128, HID = 128, OUT = 64;
    int N = in_sizes[0] / IN;
    int E = in_sizes[1] / 2;
    const int* srcp = ei;
    const int* dstp = ei + E;

    char* p = (char*)d_ws;
    auto alloc = [&](size_t bytes) {
        char* r = p;
        p += (bytes + 255) & ~(size_t)255;
        return r;
    };
    int*   rowptr = (int*)alloc((size_t)(N + 1) * 4);
    int*   pos    = (int*)alloc((size_t)N * 4);
    int*   colv   = (int*)alloc((size_t)E * 4);
    float* normv  = (float*)alloc((size_t)E * 4);
    float* dinv   = (float*)alloc((size_t)N * 4);
    float* hbuf   = (float*)alloc((size_t)N * HID * 4);
    float* abuf   = (float*)alloc((size_t)N * HID * 4);

    // --- CSR build (once; shared by all 3 layers) ---
    hipMemsetAsync(rowptr, 0, (size_t)(N + 1) * 4, stream);
    hist_kernel<<<(E + 255) / 256, 256, 0, stream>>>(dstp, rowptr, E);
    dinv_kernel<<<(N + 255) / 256, 256, 0, stream>>>(rowptr, dinv, N);
    scan_kernel<<<1, 1024, 0, stream>>>(rowptr, N);
    initpos_kernel<<<(N + 255) / 256, 256, 0, stream>>>(rowptr, pos, N);
    scatter_kernel<<<(E + 255) / 256, 256, 0, stream>>>(srcp, dstp, dinv, pos, colv, normv, E);

    int nwave_blocks = (N + 3) / 4;

    // --- layer 1 ---
    dim3 g1((N + 63) / 64, HID / 64);
    gemm_kernel<<<g1, 256, 0, stream>>>(x, W1, hbuf, N, IN, HID);
    spmm128_kernel<<<nwave_blocks, 256, 0, stream>>>(hbuf, rowptr, colv, normv, dinv, b1, abuf, N);

    // --- layer 2 ---
    gemm_kernel<<<g1, 256, 0, stream>>>(abuf, W2, hbuf, N, HID, HID);
    spmm128_kernel<<<nwave_blocks, 256, 0, stream>>>(hbuf, rowptr, colv, normv, dinv, b2, abuf, N);

    // --- layer 3 (fused bias+relu+log_softmax) ---
    dim3 g3((N + 63) / 64, OUT / 64);
    gemm_kernel<<<g3, 256, 0, stream>>>(abuf, W3, hbuf, N, HID, OUT);
    spmm64_lsm_kernel<<<nwave_blocks, 256, 0, stream>>>(hbuf, rowptr, colv, normv, dinv, b3, out, N);
}

// Round 2
// 392.166 us; speedup vs baseline: 1.4493x; 1.4493x over previous
//
#include <hip/hip_runtime.h>
#include <math.h>

// ---------------------------------------------------------------------------
// GCN 3-layer forward for MI355X.
// CSR (dst-grouped) + per-edge norm built once, reused by all 3 layers.
// Dense transform = fp32 tiled GEMM (no fp32 MFMA on CDNA4).
// Aggregation = CSR gather SpMM, one wave per node, 8 gathers in flight.
// Layer 3 fuses bias+relu+log_softmax (64 cols == 64 lanes).
// ---------------------------------------------------------------------------

__global__ void hist_kernel(const int* __restrict__ dst, int* __restrict__ counts, int E) {
    int e = blockIdx.x * blockDim.x + threadIdx.x;
    if (e < E) atomicAdd(&counts[dst[e]], 1);
}

__global__ void dinv_kernel(const int* __restrict__ counts, float* __restrict__ dinv, int N) {
    int v = blockIdx.x * blockDim.x + threadIdx.x;
    if (v < N) dinv[v] = rsqrtf((float)counts[v] + 1.0f);  // +1 self loop
}

// --- 3-phase exclusive scan: deg[0..n-1] -> rowptr[0..n], pos[i]=rowptr[i] ---
__global__ __launch_bounds__(1024) void scan_phase1(const int* __restrict__ deg,
                                                    int* __restrict__ rowptr,
                                                    int* __restrict__ part, int n) {
    __shared__ int buf[1024];
    int tid = threadIdx.x;
    int i = blockIdx.x * 1024 + tid;
    int v = (i < n) ? deg[i] : 0;
    buf[tid] = v;
    __syncthreads();
    #pragma unroll
    for (int off = 1; off < 1024; off <<= 1) {
        int t = (tid >= off) ? buf[tid - off] : 0;
        __syncthreads();
        buf[tid] += t;
        __syncthreads();
    }
    if (i < n) rowptr[i] = buf[tid] - v;          // exclusive within chunk
    if (tid == 1023) part[blockIdx.x] = buf[1023]; // chunk total
}

__global__ __launch_bounds__(1024) void scan_phase2(int* __restrict__ part, int nchunks) {
    __shared__ int buf[1024];
    int tid = threadIdx.x;
    int v = (tid < nchunks) ? part[tid] : 0;
    buf[tid] = v;
    __syncthreads();
    #pragma unroll
    for (int off = 1; off < 1024; off <<= 1) {
        int t = (tid >= off) ? buf[tid - off] : 0;
        __syncthreads();
        buf[tid] += t;
        __syncthreads();
    }
    if (tid < nchunks) part[tid] = buf[tid] - v;   // exclusive chunk offsets
    if (tid == 1023) part[nchunks] = buf[1023];    // grand total
}

__global__ void scan_phase3(int* __restrict__ rowptr, int* __restrict__ pos,
                            const int* __restrict__ part, int n, int nchunks) {
    int i = blockIdx.x * blockDim.x + threadIdx.x;
    if (i < n) {
        int r = rowptr[i] + part[i >> 10];
        rowptr[i] = r;
        pos[i] = r;
    } else if (i == n) {
        rowptr[n] = part[nchunks];
    }
}

// pack (src, norm) as int2 so the SpMM does one 8B load per edge
__global__ void scatter_kernel(const int* __restrict__ src, const int* __restrict__ dst,
                               const float* __restrict__ dinv, int* __restrict__ pos,
                               int2* __restrict__ ep, int E) {
    int e = blockIdx.x * blockDim.x + threadIdx.x;
    if (e >= E) return;
    int s = src[e], d = dst[e];
    int idx = atomicAdd(&pos[d], 1);
    ep[idx] = make_int2(s, __float_as_int(dinv[s] * dinv[d]));
}

// C[N][H] = A[N][K] @ B[K][H]; 64x64 tile, K-step 32, 256 threads, 4x4 micro.
__global__ __launch_bounds__(256) void gemm_kernel(const float* __restrict__ A,
                                                   const float* __restrict__ B,
                                                   float* __restrict__ C,
                                                   int N, int K, int H) {
    __shared__ float As[64][33];
    __shared__ float Bs[32][65];
    int row0 = blockIdx.x * 64, col0 = blockIdx.y * 64;
    int tid = threadIdx.x;
    int tx = tid & 15, ty = tid >> 4;
    float acc[4][4] = {};
    for (int k0 = 0; k0 < K; k0 += 32) {
        for (int i = tid; i < 64 * 32; i += 256) {
            int r = i >> 5, c = i & 31;
            int gr = row0 + r;
            As[r][c] = (gr < N) ? A[(size_t)gr * K + k0 + c] : 0.0f;
        }
        for (int i = tid; i < 32 * 64; i += 256) {
            int r = i >> 6, c = i & 63;
            Bs[r][c] = B[(size_t)(k0 + r) * H + col0 + c];
        }
        __syncthreads();
        #pragma unroll
        for (int kk = 0; kk < 32; ++kk) {
            float a[4], b[4];
            #pragma unroll
            for (int i = 0; i < 4; ++i) a[i] = As[ty * 4 + i][kk];
            #pragma unroll
            for (int j = 0; j < 4; ++j) b[j] = Bs[kk][tx * 4 + j];
            #pragma unroll
            for (int i = 0; i < 4; ++i)
                #pragma unroll
                for (int j = 0; j < 4; ++j) acc[i][j] += a[i] * b[j];
        }
        __syncthreads();
    }
    #pragma unroll
    for (int i = 0; i < 4; ++i) {
        int gr = row0 + ty * 4 + i;
        if (gr < N) {
            #pragma unroll
            for (int j = 0; j < 4; ++j)
                C[(size_t)gr * H + col0 + tx * 4 + j] = acc[i][j];
        }
    }
}

// One wave per node, 128 channels via float2, 8 gathers in flight.
__global__ __launch_bounds__(256) void spmm128_kernel(const float* __restrict__ h,
                                                      const int* __restrict__ rowptr,
                                                      const int2* __restrict__ ep,
                                                      const float* __restrict__ dinv,
                                                      const float* __restrict__ bias,
                                                      float* __restrict__ out, int N) {
    int wid = blockIdx.x * 4 + (threadIdx.x >> 6);
    int lane = threadIdx.x & 63;
    if (wid >= N) return;
    const float2* h2 = (const float2*)h;
    float dv = dinv[wid];
    float w = dv * dv;
    float2 hv = h2[(size_t)wid * 64 + lane];
    float ax = hv.x * w, ay = hv.y * w;
    int beg = rowptr[wid], end = rowptr[wid + 1];
    int e = beg;
    for (; e + 8 <= end; e += 8) {
        int2 ed[8];
        float2 g[8];
        #pragma unroll
        for (int u = 0; u < 8; ++u) ed[u] = ep[e + u];
        #pragma unroll
        for (int u = 0; u < 8; ++u) g[u] = h2[(size_t)ed[u].x * 64 + lane];
        #pragma unroll
        for (int u = 0; u < 8; ++u) {
            float nm = __int_as_float(ed[u].y);
            ax += g[u].x * nm;
            ay += g[u].y * nm;
        }
    }
    if (e < end) {  // masked tail: dummy slots reuse edge e (L1 hit, norm=0)
        int cnt = end - e;
        int2 ed[8];
        float2 g[8];
        #pragma unroll
        for (int u = 0; u < 8; ++u) ed[u] = ep[(u < cnt) ? e + u : e];
        #pragma unroll
        for (int u = 0; u < 8; ++u) g[u] = h2[(size_t)ed[u].x * 64 + lane];
        #pragma unroll
        for (int u = 0; u < 8; ++u) {
            float nm = (u < cnt) ? __int_as_float(ed[u].y) : 0.0f;
            ax += g[u].x * nm;
            ay += g[u].y * nm;
        }
    }
    ax += bias[lane * 2];
    ay += bias[lane * 2 + 1];
    float2 o;
    o.x = fmaxf(ax, 0.0f);
    o.y = fmaxf(ay, 0.0f);
    ((float2*)out)[(size_t)wid * 64 + lane] = o;
}

// Layer 3: 64 channels (one per lane) + bias + relu + log_softmax across lanes.
__global__ __launch_bounds__(256) void spmm64_lsm_kernel(const float* __restrict__ h,
                                                         const int* __restrict__ rowptr,
                                                         const int2* __restrict__ ep,
                                                         const float* __restrict__ dinv,
                                                         const float* __restrict__ bias,
                                                         float* __restrict__ out, int N) {
    int wid = blockIdx.x * 4 + (threadIdx.x >> 6);
    int lane = threadIdx.x & 63;
    if (wid >= N) return;
    float dv = dinv[wid];
    float acc = h[(size_t)wid * 64 + lane] * dv * dv;
    int beg = rowptr[wid], end = rowptr[wid + 1];
    int e = beg;
    for (; e + 8 <= end; e += 8) {
        int2 ed[8];
        float g[8];
        #pragma unroll
        for (int u = 0; u < 8; ++u) ed[u] = ep[e + u];
        #pragma unroll
        for (int u = 0; u < 8; ++u) g[u] = h[(size_t)ed[u].x * 64 + lane];
        #pragma unroll
        for (int u = 0; u < 8; ++u) acc += g[u] * __int_as_float(ed[u].y);
    }
    if (e < end) {
        int cnt = end - e;
        int2 ed[8];
        float g[8];
        #pragma unroll
        for (int u = 0; u < 8; ++u) ed[u] = ep[(u < cnt) ? e + u : e];
        #pragma unroll
        for (int u = 0; u < 8; ++u) g[u] = h[(size_t)ed[u].x * 64 + lane];
        #pragma unroll
        for (int u = 0; u < 8; ++u) {
            float nm = (u < cnt) ? __int_as_float(ed[u].y) : 0.0f;
            acc += g[u] * nm;
        }
    }
    acc += bias[lane];
    acc = fmaxf(acc, 0.0f);
    float m = acc;
    #pragma unroll
    for (int off = 32; off; off >>= 1) m = fmaxf(m, __shfl_xor(m, off));
    float ex = expf(acc - m);
    float ssum = ex;
    #pragma unroll
    for (int off = 32; off; off >>= 1) ssum += __shfl_xor(ssum, off);
    out[(size_t)wid * 64 + lane] = acc - m - logf(ssum);
}

extern "C" void kernel_launch(void* const* d_in, const int* in_sizes, int n_in,
                              void* d_out, int out_size, void* d_ws, size_t ws_size,
                              hipStream_t stream) {
    const float* x  = (const float*)d_in[0];
    const int*   ei = (const int*)d_in[1];
    const float* W1 = (const float*)d_in[2];
    const float* b1 = (const float*)d_in[3];
    const float* W2 = (const float*)d_in[4];
    const float* b2 = (const float*)d_in[5];
    const float* W3 = (const float*)d_in[6];
    const float* b3 = (const float*)d_in[7];
    float* out = (float*)d_out;

    const int IN = 128, HID = 128, OUT = 64;
    int N = in_sizes[0] / IN;
    int E = in_sizes[1] / 2;
    const int* srcp = ei;
    const int* dstp = ei + E;

    char* p = (char*)d_ws;
    auto alloc = [&](size_t bytes) {
        char* r = p;
        p += (bytes + 255) & ~(size_t)255;
        return r;
    };
    int*   deg    = (int*)alloc((size_t)N * 4);
    int*   rowptr = (int*)alloc((size_t)(N + 1) * 4);
    int*   pos    = (int*)alloc((size_t)N * 4);
    int*   part   = (int*)alloc((size_t)1025 * 4);
    int2*  epack  = (int2*)alloc((size_t)E * 8);
    float* dinv   = (float*)alloc((size_t)N * 4);
    float* hbuf   = (float*)alloc((size_t)N * HID * 4);
    float* abuf   = (float*)alloc((size_t)N * HID * 4);

    // --- CSR build (once; shared by all 3 layers) ---
    hipMemsetAsync(deg, 0, (size_t)N * 4, stream);
    hist_kernel<<<(E + 255) / 256, 256, 0, stream>>>(dstp, deg, E);
    dinv_kernel<<<(N + 255) / 256, 256, 0, stream>>>(deg, dinv, N);
    int nchunks = (N + 1023) / 1024;
    scan_phase1<<<nchunks, 1024, 0, stream>>>(deg, rowptr, part, N);
    scan_phase2<<<1, 1024, 0, stream>>>(part, nchunks);
    scan_phase3<<<(N + 256) / 256, 256, 0, stream>>>(rowptr, pos, part, N, nchunks);
    scatter_kernel<<<(E + 255) / 256, 256, 0, stream>>>(srcp, dstp, dinv, pos, epack, E);

    int nwave_blocks = (N + 3) / 4;

    // --- layer 1 ---
    dim3 g1((N + 63) / 64, HID / 64);
    gemm_kernel<<<g1, 256, 0, stream>>>(x, W1, hbuf, N, IN, HID);
    spmm128_kernel<<<nwave_blocks, 256, 0, stream>>>(hbuf, rowptr, epack, dinv, b1, abuf, N);

    // --- layer 2 ---
    gemm_kernel<<<g1, 256, 0, stream>>>(abuf, W2, hbuf, N, HID, HID);
    spmm128_kernel<<<nwave_blocks, 256, 0, stream>>>(hbuf, rowptr, epack, dinv, b2, abuf, N);

    // --- layer 3 (fused bias+relu+log_softmax) ---
    dim3 g3((N + 63) / 64, OUT / 64);
    gemm_kernel<<<g3, 256, 0, stream>>>(abuf, W3, hbuf, N, HID, OUT);
    spmm64_lsm_kernel<<<nwave_blocks, 256, 0, stream>>>(hbuf, rowptr, epack, dinv, b3, out, N);
}

// Round 3
// 246.599 us; speedup vs baseline: 2.3049x; 1.5903x over previous
//
#include <hip/hip_runtime.h>
#include <math.h>

// ---------------------------------------------------------------------------
// GCN 3-layer forward for MI355X — bf16 MFMA edition.
// CSR (dst-grouped) + per-edge norm built once, reused by all 3 layers.
// Dense transform = bf16 MFMA GEMM (16x16x32), fp32 accum, bf16 h.
// Aggregation = CSR gather SpMM over bf16 rows (256B/row), fp32 accum.
// Layer 3 fuses bias+relu+log_softmax (64 cols == 64 lanes).
// ---------------------------------------------------------------------------

typedef __attribute__((ext_vector_type(8))) short short8;
typedef __attribute__((ext_vector_type(4))) float f32x4;

__device__ inline unsigned short f2bf(float x) {
    unsigned int u = __float_as_uint(x);
    u += 0x7fffu + ((u >> 16) & 1u);   // round to nearest even
    return (unsigned short)(u >> 16);
}
__device__ inline float bf2f(unsigned short v) {
    return __uint_as_float((unsigned int)v << 16);
}

// ------------------------------- prep ---------------------------------------

__global__ void hist_kernel(const int* __restrict__ dst, int* __restrict__ counts, int E) {
    int e = blockIdx.x * blockDim.x + threadIdx.x;
    if (e < E) atomicAdd(&counts[dst[e]], 1);
}

__global__ void dinv_kernel(const int* __restrict__ counts, float* __restrict__ dinv, int N) {
    int v = blockIdx.x * blockDim.x + threadIdx.x;
    if (v < N) dinv[v] = rsqrtf((float)counts[v] + 1.0f);  // +1 self loop
}

__global__ __launch_bounds__(1024) void scan_phase1(const int* __restrict__ deg,
                                                    int* __restrict__ rowptr,
                                                    int* __restrict__ part, int n) {
    __shared__ int buf[1024];
    int tid = threadIdx.x;
    int i = blockIdx.x * 1024 + tid;
    int v = (i < n) ? deg[i] : 0;
    buf[tid] = v;
    __syncthreads();
    #pragma unroll
    for (int off = 1; off < 1024; off <<= 1) {
        int t = (tid >= off) ? buf[tid - off] : 0;
        __syncthreads();
        buf[tid] += t;
        __syncthreads();
    }
    if (i < n) rowptr[i] = buf[tid] - v;
    if (tid == 1023) part[blockIdx.x] = buf[1023];
}

__global__ __launch_bounds__(1024) void scan_phase2(int* __restrict__ part, int nchunks) {
    __shared__ int buf[1024];
    int tid = threadIdx.x;
    int v = (tid < nchunks) ? part[tid] : 0;
    buf[tid] = v;
    __syncthreads();
    #pragma unroll
    for (int off = 1; off < 1024; off <<= 1) {
        int t = (tid >= off) ? buf[tid - off] : 0;
        __syncthreads();
        buf[tid] += t;
        __syncthreads();
    }
    if (tid < nchunks) part[tid] = buf[tid] - v;
    if (tid == 1023) part[nchunks] = buf[1023];
}

__global__ void scan_phase3(int* __restrict__ rowptr, int* __restrict__ pos,
                            const int* __restrict__ part, int n, int nchunks) {
    int i = blockIdx.x * blockDim.x + threadIdx.x;
    if (i < n) {
        int r = rowptr[i] + part[i >> 10];
        rowptr[i] = r;
        pos[i] = r;
    } else if (i == n) {
        rowptr[n] = part[nchunks];
    }
}

__global__ void scatter_kernel(const int* __restrict__ src, const int* __restrict__ dst,
                               const float* __restrict__ dinv, int* __restrict__ pos,
                               int2* __restrict__ ep, int E) {
    int e = blockIdx.x * blockDim.x + threadIdx.x;
    if (e >= E) return;
    int s = src[e], d = dst[e];
    int idx = atomicAdd(&pos[d], 1);
    ep[idx] = make_int2(s, __float_as_int(dinv[s] * dinv[d]));
}

__global__ void cast_bf16_kernel(const float* __restrict__ in, unsigned short* __restrict__ out,
                                 int n4) {  // n4 = n/4
    int i = blockIdx.x * blockDim.x + threadIdx.x;
    if (i < n4) {
        float4 v = *(const float4*)(in + (size_t)i * 4);
        ushort4 o;
        o.x = f2bf(v.x); o.y = f2bf(v.y); o.z = f2bf(v.z); o.w = f2bf(v.w);
        *(ushort4*)(out + (size_t)i * 4) = o;
    }
}

// Wt[n][k] = bf16(W[k][n]);  W is [K][H]
__global__ void transpose_cast_kernel(const float* __restrict__ W, unsigned short* __restrict__ Wt,
                                      int K, int H) {
    int i = blockIdx.x * blockDim.x + threadIdx.x;
    if (i < K * H) {
        int k = i / H, n = i - k * H;
        Wt[(size_t)n * K + k] = f2bf(W[i]);
    }
}

// ------------------------------ bf16 MFMA GEMM ------------------------------
// C[M][H] = A[M][128] @ W[128][H], A & Wt bf16, C bf16. Wt = W^T stored [H][128].
// BM=64, 256 threads (4 waves), wave owns a 16-row tile x all H cols.
// Verified fragment layout (learn_hip m89/m92): A-frag lane l, elem j ->
// A[l&15][8*(l>>4)+j]; B-frag -> B[8*(l>>4)+j][l&15] (= Wt[l&15][8*(l>>4)+j]);
// D lane l reg r -> D[4*(l>>4)+r][l&15].
template<int H>
__global__ __launch_bounds__(256) void gemm_mfma(const unsigned short* __restrict__ A,
                                                 const unsigned short* __restrict__ Wt,
                                                 unsigned short* __restrict__ C, int M) {
    __shared__ __attribute__((aligned(16))) unsigned short As[64][136];  // +8 pad: b128 reads conflict-free
    __shared__ __attribute__((aligned(16))) unsigned short Ws[H][136];
    int tid = threadIdx.x;
    int row0 = blockIdx.x * 64;
    // stage A tile (64x128 bf16) as 16B chunks
    #pragma unroll
    for (int g = tid; g < 64 * 16; g += 256) {
        int r = g >> 4, c = g & 15;
        int gr = row0 + r;
        uint4 v = make_uint4(0, 0, 0, 0);
        if (gr < M) v = *(const uint4*)(A + (size_t)gr * 128 + c * 8);
        *(uint4*)&As[r][c * 8] = v;
    }
    // stage Wt (Hx128 bf16)
    #pragma unroll
    for (int g = tid; g < H * 16; g += 256) {
        int r = g >> 4, c = g & 15;
        *(uint4*)&Ws[r][c * 8] = *(const uint4*)(Wt + (size_t)r * 128 + c * 8);
    }
    __syncthreads();

    int wave = tid >> 6, lane = tid & 63;
    int lr = lane & 15;
    int lk = (lane >> 4) * 8;     // k sub-offset within 32-wide k-step
    int rt = wave * 16;           // this wave's row tile

    short8 af[4];
    #pragma unroll
    for (int ks = 0; ks < 4; ++ks)
        af[ks] = *(const short8*)&As[rt + lr][ks * 32 + lk];

    #pragma unroll
    for (int ct = 0; ct < H / 16; ++ct) {
        f32x4 acc = {0.f, 0.f, 0.f, 0.f};
        #pragma unroll
        for (int ks = 0; ks < 4; ++ks) {
            short8 wf = *(const short8*)&Ws[ct * 16 + lr][ks * 32 + lk];
            acc = __builtin_amdgcn_mfma_f32_16x16x32_bf16(af[ks], wf, acc, 0, 0, 0);
        }
        int gcol = ct * 16 + lr;
        #pragma unroll
        for (int r = 0; r < 4; ++r) {
            int grow = row0 + rt + (lane >> 4) * 4 + r;
            if (grow < M) C[(size_t)grow * H + gcol] = f2bf(acc[r]);
        }
    }
}

// ------------------------------- SpMM ---------------------------------------
// h is bf16 [N][128] viewed as uint [N][64]; one wave per node; 8 gathers in flight.
__global__ __launch_bounds__(256) void spmm128_kernel(const unsigned int* __restrict__ h32,
                                                      const int* __restrict__ rowptr,
                                                      const int2* __restrict__ ep,
                                                      const float* __restrict__ dinv,
                                                      const float* __restrict__ bias,
                                                      unsigned int* __restrict__ out32, int N) {
    int wid = blockIdx.x * 4 + (threadIdx.x >> 6);
    int lane = threadIdx.x & 63;
    if (wid >= N) return;
    float dv = dinv[wid];
    float w = dv * dv;
    unsigned int hv = h32[(size_t)wid * 64 + lane];
    float ax = bf2f((unsigned short)(hv & 0xffff)) * w;
    float ay = bf2f((unsigned short)(hv >> 16)) * w;
    int beg = rowptr[wid], end = rowptr[wid + 1];
    int e = beg;
    for (; e + 8 <= end; e += 8) {
        int2 ed[8];
        unsigned int g[8];
        #pragma unroll
        for (int u = 0; u < 8; ++u) ed[u] = ep[e + u];
        #pragma unroll
        for (int u = 0; u < 8; ++u) g[u] = h32[(size_t)ed[u].x * 64 + lane];
        #pragma unroll
        for (int u = 0; u < 8; ++u) {
            float nm = __int_as_float(ed[u].y);
            ax += bf2f((unsigned short)(g[u] & 0xffff)) * nm;
            ay += bf2f((unsigned short)(g[u] >> 16)) * nm;
        }
    }
    if (e < end) {  // masked tail: dummy slots re-read edge e (L1 hit, norm=0)
        int cnt = end - e;
        int2 ed[8];
        unsigned int g[8];
        #pragma unroll
        for (int u = 0; u < 8; ++u) ed[u] = ep[(u < cnt) ? e + u : e];
        #pragma unroll
        for (int u = 0; u < 8; ++u) g[u] = h32[(size_t)ed[u].x * 64 + lane];
        #pragma unroll
        for (int u = 0; u < 8; ++u) {
            float nm = (u < cnt) ? __int_as_float(ed[u].y) : 0.0f;
            ax += bf2f((unsigned short)(g[u] & 0xffff)) * nm;
            ay += bf2f((unsigned short)(g[u] >> 16)) * nm;
        }
    }
    ax += bias[lane * 2];
    ay += bias[lane * 2 + 1];
    ax = fmaxf(ax, 0.0f);
    ay = fmaxf(ay, 0.0f);
    out32[(size_t)wid * 64 + lane] = (unsigned int)f2bf(ax) | ((unsigned int)f2bf(ay) << 16);
}

// Layer 3: h bf16 [N][64]; bias + relu + log_softmax across 64 lanes; fp32 out.
__global__ __launch_bounds__(256) void spmm64_lsm_kernel(const unsigned short* __restrict__ h16,
                                                         const int* __restrict__ rowptr,
                                                         const int2* __restrict__ ep,
                                                         const float* __restrict__ dinv,
                                                         const float* __restrict__ bias,
                                                         float* __restrict__ out, int N) {
    int wid = blockIdx.x * 4 + (threadIdx.x >> 6);
    int lane = threadIdx.x & 63;
    if (wid >= N) return;
    float dv = dinv[wid];
    float acc = bf2f(h16[(size_t)wid * 64 + lane]) * dv * dv;
    int beg = rowptr[wid], end = rowptr[wid + 1];
    int e = beg;
    for (; e + 8 <= end; e += 8) {
        int2 ed[8];
        unsigned short g[8];
        #pragma unroll
        for (int u = 0; u < 8; ++u) ed[u] = ep[e + u];
        #pragma unroll
        for (int u = 0; u < 8; ++u) g[u] = h16[(size_t)ed[u].x * 64 + lane];
        #pragma unroll
        for (int u = 0; u < 8; ++u) acc += bf2f(g[u]) * __int_as_float(ed[u].y);
    }
    if (e < end) {
        int cnt = end - e;
        int2 ed[8];
        unsigned short g[8];
        #pragma unroll
        for (int u = 0; u < 8; ++u) ed[u] = ep[(u < cnt) ? e + u : e];
        #pragma unroll
        for (int u = 0; u < 8; ++u) g[u] = h16[(size_t)ed[u].x * 64 + lane];
        #pragma unroll
        for (int u = 0; u < 8; ++u) {
            float nm = (u < cnt) ? __int_as_float(ed[u].y) : 0.0f;
            acc += bf2f(g[u]) * nm;
        }
    }
    acc += bias[lane];
    acc = fmaxf(acc, 0.0f);
    float m = acc;
    #pragma unroll
    for (int off = 32; off; off >>= 1) m = fmaxf(m, __shfl_xor(m, off));
    float ex = expf(acc - m);
    float ssum = ex;
    #pragma unroll
    for (int off = 32; off; off >>= 1) ssum += __shfl_xor(ssum, off);
    out[(size_t)wid * 64 + lane] = acc - m - logf(ssum);
}

// ------------------------------- launch -------------------------------------

extern "C" void kernel_launch(void* const* d_in, const int* in_sizes, int n_in,
                              void* d_out, int out_size, void* d_ws, size_t ws_size,
                              hipStream_t stream) {
    const float* x  = (const float*)d_in[0];
    const int*   ei = (const int*)d_in[1];
    const float* W1 = (const float*)d_in[2];
    const float* b1 = (const float*)d_in[3];
    const float* W2 = (const float*)d_in[4];
    const float* b2 = (const float*)d_in[5];
    const float* W3 = (const float*)d_in[6];
    const float* b3 = (const float*)d_in[7];
    float* out = (float*)d_out;

    const int IN = 128, HID = 128, OUT = 64;
    int N = in_sizes[0] / IN;
    int E = in_sizes[1] / 2;
    const int* srcp = ei;
    const int* dstp = ei + E;

    char* p = (char*)d_ws;
    auto alloc = [&](size_t bytes) {
        char* r = p;
        p += (bytes + 255) & ~(size_t)255;
        return r;
    };
    int*   deg    = (int*)alloc((size_t)N * 4);
    int*   rowptr = (int*)alloc((size_t)(N + 1) * 4);
    int*   pos    = (int*)alloc((size_t)N * 4);
    int*   part   = (int*)alloc((size_t)1025 * 4);
    int2*  epack  = (int2*)alloc((size_t)E * 8);
    float* dinv   = (float*)alloc((size_t)N * 4);
    unsigned short* xb   = (unsigned short*)alloc((size_t)N * IN * 2);
    unsigned short* W1t  = (unsigned short*)alloc((size_t)IN * HID * 2);
    unsigned short* W2t  = (unsigned short*)alloc((size_t)HID * HID * 2);
    unsigned short* W3t  = (unsigned short*)alloc((size_t)HID * OUT * 2);
    unsigned short* hbuf = (unsigned short*)alloc((size_t)N * HID * 2);
    unsigned short* abuf = (unsigned short*)alloc((size_t)N * HID * 2);

    // --- CSR build (once; shared by all 3 layers) ---
    hipMemsetAsync(deg, 0, (size_t)N * 4, stream);
    hist_kernel<<<(E + 255) / 256, 256, 0, stream>>>(dstp, deg, E);
    dinv_kernel<<<(N + 255) / 256, 256, 0, stream>>>(deg, dinv, N);
    int nchunks = (N + 1023) / 1024;
    scan_phase1<<<nchunks, 1024, 0, stream>>>(deg, rowptr, part, N);
    scan_phase2<<<1, 1024, 0, stream>>>(part, nchunks);
    scan_phase3<<<(N + 256) / 256, 256, 0, stream>>>(rowptr, pos, part, N, nchunks);
    scatter_kernel<<<(E + 255) / 256, 256, 0, stream>>>(srcp, dstp, dinv, pos, epack, E);

    // --- bf16 prep: cast x, transpose+cast weights ---
    cast_bf16_kernel<<<(N * IN / 4 + 255) / 256, 256, 0, stream>>>(x, xb, N * IN / 4);
    transpose_cast_kernel<<<(IN * HID + 255) / 256, 256, 0, stream>>>(W1, W1t, IN, HID);
    transpose_cast_kernel<<<(HID * HID + 255) / 256, 256, 0, stream>>>(W2, W2t, HID, HID);
    transpose_cast_kernel<<<(HID * OUT + 255) / 256, 256, 0, stream>>>(W3, W3t, HID, OUT);

    int nwave_blocks = (N + 3) / 4;
    int gemm_blocks = (N + 63) / 64;

    // --- layer 1 ---
    gemm_mfma<128><<<gemm_blocks, 256, 0, stream>>>(xb, W1t, hbuf, N);
    spmm128_kernel<<<nwave_blocks, 256, 0, stream>>>((const unsigned int*)hbuf, rowptr, epack,
                                                     dinv, b1, (unsigned int*)abuf, N);
    // --- layer 2 ---
    gemm_mfma<128><<<gemm_blocks, 256, 0, stream>>>(abuf, W2t, hbuf, N);
    spmm128_kernel<<<nwave_blocks, 256, 0, stream>>>((const unsigned int*)hbuf, rowptr, epack,
                                                     dinv, b2, (unsigned int*)abuf, N);
    // --- layer 3 (fused bias+relu+log_softmax) ---
    gemm_mfma<64><<<gemm_blocks, 256, 0, stream>>>(abuf, W3t, hbuf, N);
    spmm64_lsm_kernel<<<nwave_blocks, 256, 0, stream>>>(hbuf, rowptr, epack, dinv, b3, out, N);
}